// Round 11
// baseline (688.864 us; speedup 1.0000x reference)
//
#include <hip/hip_runtime.h>
#include <math.h>

// ---------------------------------------------------------------------------
// Fused transformer block w/ MoE (B=2,T=2048,C=1024,H=16,D=64,E=8,topK=2)
// Round 11: r10 high-TLP GEMM (single-buf 128x128/BK=32, 6 blocks/CU) +
// expert==XCD 1-D block swizzle for fc/pj (rowblock-fastest for B-panel L2
// reuse). Dense qkv/proj and attn unchanged.
// ---------------------------------------------------------------------------

typedef __bf16 b16v8 __attribute__((ext_vector_type(8)));
typedef float f32x4 __attribute__((ext_vector_type(4)));

#define MFMA(a, b, c) __builtin_amdgcn_mfma_f32_16x16x32_bf16(a, b, c, 0, 0, 0)

#define GLOAD_LDS16(g, l)                                          \
  __builtin_amdgcn_global_load_lds(                                \
      (const __attribute__((address_space(1))) void*)(g),          \
      (__attribute__((address_space(3))) void*)(l), 16, 0, 0)

constexpr int Bc = 2, Tc = 2048, Cc = 1024, Hc = 16, Dc = 64;
constexpr int Nc = Bc * Tc;       // 4096 tokens
constexpr int HIDc = 4096;        // 4*C
constexpr int Ec = 8;
constexpr int NPAIR = Nc * 2;     // 8192
constexpr float LOG2E = 1.4426950408889634f;

__device__ inline unsigned short f32_bf16(float f) {
  union { float f; unsigned u; } x; x.f = f;
  unsigned r = x.u + 0x7fffu + ((x.u >> 16) & 1u);   // RNE
  return (unsigned short)(r >> 16);
}

// gelu(x) = x * sigmoid(1.595769122*(x+0.044715x^3)); exp2-domain
__device__ inline float gelu_f(float x) {
  float t = 2.3021188f * x * (1.f + 0.044715f * x * x);
  float e = __builtin_amdgcn_exp2f(-t);
  return x * __builtin_amdgcn_rcpf(1.f + e);
}

// BK=32 rows: 4 granules of 16B. XOR key (row>>1)&3 -> 2 lanes/bank-quad.
__device__ inline int swz32(int row, int g) {
  return row * 32 + ((g ^ ((row >> 1) & 3)) * 8);
}

// ---------------------------------------------------------------------------
// Transpose+convert: src f32 [batch][K][N] -> dst bf16 [batch][N][K]
// ---------------------------------------------------------------------------
__global__ __launch_bounds__(256) void convT_kernel(
    const float* __restrict__ src, unsigned short* __restrict__ dst,
    int K, int N) {
  const size_t sb = (size_t)blockIdx.z * K * N;
  const int n0 = blockIdx.x * 32, k0 = blockIdx.y * 32;
  __shared__ float t[32][33];
  const int tx = threadIdx.x & 31, ty = threadIdx.x >> 5;
#pragma unroll
  for (int j = 0; j < 4; ++j)
    t[ty + j * 8][tx] = src[sb + (size_t)(k0 + ty + j * 8) * N + n0 + tx];
  __syncthreads();
#pragma unroll
  for (int j = 0; j < 4; ++j)
    dst[sb + (size_t)(n0 + ty + j * 8) * K + k0 + tx] = f32_bf16(t[tx][ty + j * 8]);
}

// ---------------------------------------------------------------------------
// LayerNorm (f32 in -> bf16 out).
// ---------------------------------------------------------------------------
__global__ __launch_bounds__(256) void ln1_kernel(
    const float* __restrict__ x, const float* __restrict__ g,
    const float* __restrict__ b, unsigned short* __restrict__ out) {
  const int row = blockIdx.x;
  const int tid = threadIdx.x;
  const float* xr = x + (size_t)row * Cc;
  float v[4]; float s = 0.f, q = 0.f;
#pragma unroll
  for (int j = 0; j < 4; ++j) { v[j] = xr[tid + j * 256]; s += v[j]; q += v[j] * v[j]; }
#pragma unroll
  for (int m = 1; m <= 32; m <<= 1) { s += __shfl_xor(s, m); q += __shfl_xor(q, m); }
  __shared__ float red[2][4];
  const int w = tid >> 6;
  if ((tid & 63) == 0) { red[0][w] = s; red[1][w] = q; }
  __syncthreads();
  s = red[0][0] + red[0][1] + red[0][2] + red[0][3];
  q = red[1][0] + red[1][1] + red[1][2] + red[1][3];
  const float mean = s * (1.f / Cc);
  const float var = q * (1.f / Cc) - mean * mean;
  const float rstd = rsqrtf(var + 1e-5f);
#pragma unroll
  for (int j = 0; j < 4; ++j) {
    int c = tid + j * 256;
    out[(size_t)row * Cc + c] = f32_bf16((v[j] - mean) * rstd * g[c] + b[c]);
  }
}

// ---------------------------------------------------------------------------
// LN2 + router (f32 router math).
// ---------------------------------------------------------------------------
__global__ __launch_bounds__(256) void ln2_router_kernel(
    const float* __restrict__ x, const float* __restrict__ g,
    const float* __restrict__ b, const float* __restrict__ rw,
    unsigned short* __restrict__ out, int* __restrict__ tki, float* __restrict__ tkp) {
  const int row = blockIdx.x;
  const int tid = threadIdx.x;
  const float* xr = x + (size_t)row * Cc;
  float v[4]; float s = 0.f, q = 0.f;
#pragma unroll
  for (int j = 0; j < 4; ++j) { v[j] = xr[tid + j * 256]; s += v[j]; q += v[j] * v[j]; }
#pragma unroll
  for (int m = 1; m <= 32; m <<= 1) { s += __shfl_xor(s, m); q += __shfl_xor(q, m); }
  __shared__ float red[2][4];
  const int w = tid >> 6;
  if ((tid & 63) == 0) { red[0][w] = s; red[1][w] = q; }
  __syncthreads();
  s = red[0][0] + red[0][1] + red[0][2] + red[0][3];
  q = red[1][0] + red[1][1] + red[1][2] + red[1][3];
  const float mean = s * (1.f / Cc);
  const float var = q * (1.f / Cc) - mean * mean;
  const float rstd = rsqrtf(var + 1e-5f);
  float lg[8] = {0.f, 0.f, 0.f, 0.f, 0.f, 0.f, 0.f, 0.f};
#pragma unroll
  for (int j = 0; j < 4; ++j) {
    int c = tid + j * 256;
    float nv = (v[j] - mean) * rstd * g[c] + b[c];
    out[(size_t)row * Cc + c] = f32_bf16(nv);
    const float* rwc = rw + c * 8;
#pragma unroll
    for (int e = 0; e < 8; ++e) lg[e] += nv * rwc[e];
  }
#pragma unroll
  for (int m = 1; m <= 32; m <<= 1) {
#pragma unroll
    for (int e = 0; e < 8; ++e) lg[e] += __shfl_xor(lg[e], m);
  }
  __shared__ float rl[4][8];
  if ((tid & 63) == 0) {
#pragma unroll
    for (int e = 0; e < 8; ++e) rl[w][e] = lg[e];
  }
  __syncthreads();
  if (tid == 0) {
    float L[8];
#pragma unroll
    for (int e = 0; e < 8; ++e) L[e] = rl[0][e] + rl[1][e] + rl[2][e] + rl[3][e];
    int i1 = 0;
    for (int e = 1; e < 8; ++e) if (L[e] > L[i1]) i1 = e;
    int i2 = (i1 == 0) ? 1 : 0;
    for (int e = 0; e < 8; ++e) if (e != i1 && L[e] > L[i2]) i2 = e;
    float e2 = expf(L[i2] - L[i1]);
    float inv = 1.f / (1.f + e2);
    tki[row * 2] = i1; tki[row * 2 + 1] = i2;
    tkp[row * 2] = inv; tkp[row * 2 + 1] = e2 * inv;
  }
}

// ---------------------------------------------------------------------------
// Routing: counts -> offsets -> slot assignment (slots compact by expert).
// ---------------------------------------------------------------------------
__global__ __launch_bounds__(256) void count_kernel(
    const int* __restrict__ tki, int* __restrict__ counts) {
  int n = blockIdx.x * 256 + threadIdx.x;
  if (n >= Nc) return;
  atomicAdd(&counts[tki[n * 2]], 1);
  atomicAdd(&counts[tki[n * 2 + 1]], 1);
}

__global__ void scan_kernel(const int* __restrict__ counts,
                            int* __restrict__ eoff, int* __restrict__ cursor) {
  if (threadIdx.x == 0 && blockIdx.x == 0) {
    int s = 0;
    for (int e = 0; e < Ec; ++e) { eoff[e] = s; cursor[e] = s; s += counts[e]; }
    eoff[Ec] = s;
  }
}

__global__ __launch_bounds__(256) void assign_kernel(
    const int* __restrict__ tki, int* __restrict__ cursor,
    int* __restrict__ slot_tok, int* __restrict__ tok2slot) {
  int n = blockIdx.x * 256 + threadIdx.x;
  if (n >= Nc) return;
#pragma unroll
  for (int kk = 0; kk < 2; ++kk) {
    int e = tki[n * 2 + kk];
    int slot = atomicAdd(&cursor[e], 1);
    slot_tok[slot] = n;
    tok2slot[n * 2 + kk] = slot;
  }
}

// ---------------------------------------------------------------------------
struct GArgs {
  const unsigned short* A;    // bf16 [M][lda]
  const unsigned short* Bt;   // bf16 [N][ldb] (+ e*Bstride)
  const float* bias;          // f32 [N]      (+ e*biasStride)
  int M, N, K, lda, ldb, klen;
  size_t Bstride; int biasStride;
  const int* eoff;            // [E+1] (MODE 2/3)
  const int* slot_tok;        // (MODE 2)
  float* outF;                // MODE 1: out, MODE 3: pair buffers
  const float* resid;         // MODE 1
  unsigned short* outB;       // MODE 2: he ; MODE 0: q
  unsigned short* outK;       // MODE 0: k
  unsigned short* outV;       // MODE 0: v^T [B,H,D,T]
};

// ---------------------------------------------------------------------------
// 128x128 tile, BK=32, 4 waves (2x2), SINGLE buffer, 16 KiB LDS ->
// 6 blocks/CU. MODE 2/3: 1-D grid, expert==XCD swizzle (id&7 = hw XCD via
// round-robin dispatch), rowblock-fastest decode so co-resident blocks on
// one XCD walk consecutive rowblocks of ONE B col-panel (L2 reuse).
// MODE: 0=QKV scatter, 1=proj+resid, 2=fc gather+gelu, 3=pj split-K.
// ---------------------------------------------------------------------------
template <int MODE>
__global__ __launch_bounds__(256) void gemm128b(GArgs g) {
  int e = 0, s0 = 0, Meff = g.M, row0, col0, kh = 0;
  if constexpr (MODE == 2 || MODE == 3) {
    const int id = blockIdx.x;
    e = id & 7;                        // expert == XCD
    const int local = id >> 3;
    s0 = g.eoff[e];
    Meff = g.eoff[e + 1] - s0;
    const int nrb = (Meff + 127) >> 7; // rowblocks for this expert
    const int rb = local & 31;         // rowblock fastest (B-panel reuse)
    if (rb >= nrb) return;
    int ck = local >> 5;
    if constexpr (MODE == 3) { kh = ck & 1; ck >>= 1; }
    row0 = rb * 128;
    col0 = ck * 128;
  } else {
    row0 = blockIdx.y * 128;
    col0 = blockIdx.x * 128;
  }
  const int kbase = kh * g.klen;

  __shared__ __align__(16) unsigned short As[128 * 32];
  __shared__ __align__(16) unsigned short Bs[128 * 32];

  const int tid = threadIdx.x;
  const int lane = tid & 63, w = tid >> 6;
  const int wr = w >> 1, wc = w & 1;
  const int fr = lane & 15, fg = lane >> 4;

  const unsigned short* Bt = g.Bt + (size_t)e * g.Bstride;
  const float* bias = g.bias + (size_t)e * g.biasStride;

  // LDS dest linear (gload_lds); GLOBAL source granule pre-swizzled (#21).
  size_t aaddr[2], baddr[2];
#pragma unroll
  for (int i = 0; i < 2; ++i) {
    int pos = i * 256 + tid;                       // granule idx 0..511
    int r = pos >> 2;                              // LDS row 0..127
    int c8 = ((pos & 3) ^ ((r >> 1) & 3)) * 8;     // swizzled source (elems)
    int gr = row0 + r;
    if (gr >= Meff) gr = Meff - 1;
    int srcrow;
    if constexpr (MODE == 2) srcrow = g.slot_tok[s0 + gr];
    else if constexpr (MODE == 3) srcrow = s0 + gr;
    else srcrow = gr;
    aaddr[i] = (size_t)srcrow * g.lda + kbase + c8;
    baddr[i] = (size_t)(col0 + r) * g.ldb + kbase + c8;
  }

  auto STAGE = [&](int k0) {
#pragma unroll
    for (int i = 0; i < 2; ++i) {
      GLOAD_LDS16(g.A + aaddr[i] + k0, &As[i * 2048 + w * 512]);
      GLOAD_LDS16(Bt + baddr[i] + k0, &Bs[i * 2048 + w * 512]);
    }
  };

  f32x4 acc[4][4] = {};
  const int nt = g.klen / 32;

  for (int t = 0; t < nt; ++t) {
    if (t) __syncthreads();                 // reads of prev tile complete
    STAGE(t * 32);
    __syncthreads();                        // stage-writes landed
    b16v8 af[4], bf_[4];
#pragma unroll
    for (int mi = 0; mi < 4; ++mi)
      af[mi] = *(const b16v8*)&As[swz32(wr * 64 + mi * 16 + fr, fg)];
#pragma unroll
    for (int ni = 0; ni < 4; ++ni)
      bf_[ni] = *(const b16v8*)&Bs[swz32(wc * 64 + ni * 16 + fr, fg)];
#pragma unroll
    for (int mi = 0; mi < 4; ++mi)
#pragma unroll
      for (int ni = 0; ni < 4; ++ni)
        acc[mi][ni] = MFMA(af[mi], bf_[ni], acc[mi][ni]);
  }

  float* outF3 = nullptr;
  if constexpr (MODE == 3) outF3 = g.outF + (size_t)kh * NPAIR * Cc;

#pragma unroll
  for (int mi = 0; mi < 4; ++mi) {
#pragma unroll
    for (int ni = 0; ni < 4; ++ni) {
#pragma unroll
      for (int rr = 0; rr < 4; ++rr) {
        int row = row0 + wr * 64 + mi * 16 + fg * 4 + rr;
        int col = col0 + wc * 64 + ni * 16 + fr;
        if (row >= Meff) continue;
        float bval = bias[col];
        if constexpr (MODE == 3) { if (kh != 0) bval = 0.f; }
        float val = acc[mi][ni][rr] + bval;
        if constexpr (MODE == 0) {
          int bb = row >> 11, tt = row & (Tc - 1);
          int which = col >> 10, cj = col & (Cc - 1);
          int hd = cj >> 6, d = cj & 63;
          if (which == 0)
            g.outB[(((size_t)(bb * Hc + hd)) * Tc + tt) * Dc + d] = f32_bf16(val);
          else if (which == 1)
            g.outK[(((size_t)(bb * Hc + hd)) * Tc + tt) * Dc + d] = f32_bf16(val);
          else
            g.outV[(((size_t)(bb * Hc + hd)) * Dc + d) * Tc + tt] = f32_bf16(val);
        } else if constexpr (MODE == 1) {
          size_t o = (size_t)row * g.N + col;
          g.outF[o] = val + g.resid[o];
        } else if constexpr (MODE == 2) {
          g.outB[(size_t)(s0 + row) * g.N + col] = f32_bf16(gelu_f(val));
        } else {
          outF3[(size_t)(s0 + row) * g.N + col] = val;
        }
      }
    }
  }
}

// ---------------------------------------------------------------------------
// Flash-style causal attention. 8 waves, 128 q-rows, KV tile 64.
// T14 async-stage: next K/V tile global->reg issued before compute.
// ---------------------------------------------------------------------------
__global__ __launch_bounds__(512) void attn_kernel(
    const unsigned short* __restrict__ q, const unsigned short* __restrict__ k,
    const unsigned short* __restrict__ v, unsigned short* __restrict__ y) {
  const int qt = blockIdx.x, bh = blockIdx.y;
  const int qbase = qt * 128;
  __shared__ __align__(16) unsigned short ldsK[64][72];
  __shared__ __align__(16) unsigned short ldsVT[64][72];     // [d][kv]
  __shared__ __align__(16) unsigned short ldsP[8][16][72];
  const int tid = threadIdx.x, lane = tid & 63, w = tid >> 6;
  const int fr = lane & 15, fg = lane >> 4;
  const size_t base = (size_t)bh * Tc * Dc;
  const int qrow = qbase + w * 16 + fr;
  b16v8 qa0 = *(const b16v8*)(q + base + (size_t)qrow * Dc + fg * 8);
  b16v8 qa1 = *(const b16v8*)(q + base + (size_t)qrow * Dc + 32 + fg * 8);
  float m[4], lsum[4] = {0.f, 0.f, 0.f, 0.f};
#pragma unroll
  for (int r = 0; r < 4; ++r) m[r] = -3.0e38f;
  f32x4 oacc[4] = {};
  constexpr float SC = 0.125f * LOG2E;

  const int sr = tid >> 3, scb = (tid & 7) * 8;
  const int ntile = (qbase + 128) / 64;

  *(uint4*)&ldsK[sr][scb]  = *(const uint4*)(k + base + (size_t)sr * Dc + scb);
  *(uint4*)&ldsVT[sr][scb] = *(const uint4*)(v + base + (size_t)sr * Tc + scb);
  __syncthreads();

  for (int ti = 0; ti < ntile; ++ti) {
    const int kb = ti * 64;
    uint4 kreg, vreg;
    const bool more = (ti + 1 < ntile);
    if (more) {
      const int kn = kb + 64;
      kreg = *(const uint4*)(k + base + (size_t)(kn + sr) * Dc + scb);
      vreg = *(const uint4*)(v + base + (size_t)sr * Tc + kn + scb);
    }

    f32x4 s[4];
#pragma unroll
    for (int ni = 0; ni < 4; ++ni) {
      b16v8 kb0 = *(const b16v8*)&ldsK[ni * 16 + fr][fg * 8];
      b16v8 kb1 = *(const b16v8*)&ldsK[ni * 16 + fr][32 + fg * 8];
      f32x4 z = {};
      z = MFMA(qa0, kb0, z);
      z = MFMA(qa1, kb1, z);
      s[ni] = z;
    }
    const bool diag = (kb + 64 > qbase + w * 16);
#pragma unroll
    for (int ni = 0; ni < 4; ++ni) {
#pragma unroll
      for (int r = 0; r < 4; ++r) {
        float sv = s[ni][r] * SC;
        if (diag) {
          int gq = qbase + w * 16 + fg * 4 + r;
          int kv = kb + ni * 16 + fr;
          if (kv > gq) sv = -3.0e38f;
        }
        s[ni][r] = sv;
      }
    }
#pragma unroll
    for (int r = 0; r < 4; ++r) {
      float mx = fmaxf(fmaxf(s[0][r], s[1][r]), fmaxf(s[2][r], s[3][r]));
#pragma unroll
      for (int msk = 1; msk <= 8; msk <<= 1) mx = fmaxf(mx, __shfl_xor(mx, msk));
      float mnew = fmaxf(m[r], mx);
      float alpha = __builtin_amdgcn_exp2f(m[r] - mnew);
      float psum = 0.f;
#pragma unroll
      for (int ni = 0; ni < 4; ++ni) {
        float pp = __builtin_amdgcn_exp2f(s[ni][r] - mnew);
        s[ni][r] = pp;
        psum += pp;
      }
#pragma unroll
      for (int msk = 1; msk <= 8; msk <<= 1) psum += __shfl_xor(psum, msk);
      lsum[r] = lsum[r] * alpha + psum;
      m[r] = mnew;
#pragma unroll
      for (int ni = 0; ni < 4; ++ni) {
        oacc[ni][r] = oacc[ni][r] * alpha;
        ldsP[w][fg * 4 + r][ni * 16 + fr] = f32_bf16(s[ni][r]);
      }
    }
    asm volatile("s_waitcnt lgkmcnt(0)" ::: "memory");
    __builtin_amdgcn_sched_barrier(0);
    b16v8 pa0 = *(const b16v8*)&ldsP[w][fr][fg * 8];
    b16v8 pa1 = *(const b16v8*)&ldsP[w][fr][32 + fg * 8];
#pragma unroll
    for (int ni = 0; ni < 4; ++ni) {
      b16v8 vb0 = *(const b16v8*)&ldsVT[ni * 16 + fr][fg * 8];
      b16v8 vb1 = *(const b16v8*)&ldsVT[ni * 16 + fr][32 + fg * 8];
      oacc[ni] = MFMA(pa0, vb0, oacc[ni]);
      oacc[ni] = MFMA(pa1, vb1, oacc[ni]);
    }

    if (more) {
      __syncthreads();
      *(uint4*)&ldsK[sr][scb]  = kreg;
      *(uint4*)&ldsVT[sr][scb] = vreg;
      __syncthreads();
    }
  }

  const int bb = bh >> 4, hh = bh & 15;
#pragma unroll
  for (int r = 0; r < 4; ++r) {
    float rl = __builtin_amdgcn_rcpf(lsum[r]);
#pragma unroll
    for (int ni = 0; ni < 4; ++ni) {
      int t = qbase + w * 16 + fg * 4 + r;
      int d = ni * 16 + fr;
      y[((size_t)(bb * Tc + t)) * Cc + hh * Dc + d] = f32_bf16(oacc[ni][r] * rl);
    }
  }
}

// ---------------------------------------------------------------------------
// Deterministic combine: out[n] += p0*(pa[s0]+pb[s0]) + p1*(pa[s1]+pb[s1])
// ---------------------------------------------------------------------------
__global__ __launch_bounds__(256) void combine_kernel(
    const float* __restrict__ pair, const float* __restrict__ tkp,
    const int* __restrict__ tok2slot, float* __restrict__ out) {
  const int n = blockIdx.x;
  const int c4 = threadIdx.x * 4;
  const int s0 = tok2slot[n * 2], s1 = tok2slot[n * 2 + 1];
  const float p0 = tkp[n * 2], p1 = tkp[n * 2 + 1];
  const float* pb = pair + (size_t)NPAIR * Cc;
  float4 a0 = *(const float4*)&pair[(size_t)s0 * Cc + c4];
  float4 a1 = *(const float4*)&pb[(size_t)s0 * Cc + c4];
  float4 b0 = *(const float4*)&pair[(size_t)s1 * Cc + c4];
  float4 b1 = *(const float4*)&pb[(size_t)s1 * Cc + c4];
  float4 o = *(float4*)&out[(size_t)n * Cc + c4];
  o.x += p0 * (a0.x + a1.x) + p1 * (b0.x + b1.x);
  o.y += p0 * (a0.y + a1.y) + p1 * (b0.y + b1.y);
  o.z += p0 * (a0.z + a1.z) + p1 * (b0.z + b1.z);
  o.w += p0 * (a0.w + a1.w) + p1 * (b0.w + b1.w);
  *(float4*)&out[(size_t)n * Cc + c4] = o;
}

// ---------------------------------------------------------------------------
extern "C" void kernel_launch(void* const* d_in, const int* in_sizes, int n_in,
                              void* d_out, int out_size, void* d_ws, size_t ws_size,
                              hipStream_t stream) {
  const float* x        = (const float*)d_in[0];
  const float* ln1_g    = (const float*)d_in[1];
  const float* ln1_b    = (const float*)d_in[2];
  const float* ln2_g    = (const float*)d_in[3];
  const float* ln2_b    = (const float*)d_in[4];
  const float* attn_w   = (const float*)d_in[5];
  const float* attn_b   = (const float*)d_in[6];
  const float* proj_w   = (const float*)d_in[7];
  const float* proj_b   = (const float*)d_in[8];
  const float* router_w = (const float*)d_in[9];
  const float* fc_w     = (const float*)d_in[10];
  const float* fc_b     = (const float*)d_in[11];
  const float* pj_w     = (const float*)d_in[12];
  const float* pj_b     = (const float*)d_in[13];
  float* out = (float*)d_out;

  char* ws = (char*)d_ws;
  size_t off = 0;
  auto alloc = [&](size_t bytes) -> void* {
    void* p = ws + off;
    off = (off + bytes + 255) & ~(size_t)255;
    return p;
  };
  unsigned short* attn_wT = (unsigned short*)alloc((size_t)3 * Cc * Cc * 2);
  unsigned short* proj_wT = (unsigned short*)alloc((size_t)Cc * Cc * 2);
  unsigned short* fc_wT   = (unsigned short*)alloc((size_t)Ec * HIDc * Cc * 2);
  unsigned short* pj_wT   = (unsigned short*)alloc((size_t)Ec * Cc * HIDc * 2);
  unsigned short* h    = (unsigned short*)alloc((size_t)Nc * Cc * 2);
  unsigned short* qb   = (unsigned short*)alloc((size_t)Nc * Cc * 2);   // [B,H,T,D]
  unsigned short* kbuf = (unsigned short*)alloc((size_t)Nc * Cc * 2);   // [B,H,T,D]
  unsigned short* vbuf = (unsigned short*)alloc((size_t)Nc * Cc * 2);   // [B,H,D,T]
  unsigned short* ybuf = (unsigned short*)alloc((size_t)Nc * Cc * 2);   // [N,C]
  unsigned short* he   = (unsigned short*)alloc((size_t)NPAIR * HIDc * 2);
  float* pairout = (float*)alloc((size_t)2 * NPAIR * Cc * 4);           // 2 K-halves
  int*   tki     = (int*)alloc((size_t)Nc * 2 * 4);
  float* tkp     = (float*)alloc((size_t)Nc * 2 * 4);
  int*   counts  = (int*)alloc(Ec * 4);
  int*   eoff    = (int*)alloc((Ec + 1) * 4);
  int*   cursor  = (int*)alloc(Ec * 4);
  int*   slot_tok= (int*)alloc((size_t)NPAIR * 4);
  int*   tok2slot= (int*)alloc((size_t)Nc * 2 * 4);
  (void)ws_size; (void)in_sizes; (void)n_in; (void)out_size;

  // 0) weight pre-transpose/convert
  convT_kernel<<<dim3(3 * Cc / 32, Cc / 32, 1), 256, 0, stream>>>(attn_w, attn_wT, Cc, 3 * Cc);
  convT_kernel<<<dim3(Cc / 32, Cc / 32, 1), 256, 0, stream>>>(proj_w, proj_wT, Cc, Cc);
  convT_kernel<<<dim3(HIDc / 32, Cc / 32, Ec), 256, 0, stream>>>(fc_w, fc_wT, Cc, HIDc);
  convT_kernel<<<dim3(Cc / 32, HIDc / 32, Ec), 256, 0, stream>>>(pj_w, pj_wT, HIDc, Cc);

  // 1) LN1
  ln1_kernel<<<Nc, 256, 0, stream>>>(x, ln1_g, ln1_b, h);

  // 2) QKV GEMM -> q/k [B,H,T,D], v^T [B,H,D,T]
  {
    GArgs a = {};
    a.A = h; a.Bt = attn_wT; a.bias = attn_b;
    a.M = Nc; a.N = 3 * Cc; a.K = Cc; a.lda = Cc; a.ldb = Cc; a.klen = Cc;
    a.outB = qb; a.outK = kbuf; a.outV = vbuf;
    gemm128b<0><<<dim3(3 * Cc / 128, Nc / 128, 1), 256, 0, stream>>>(a);
  }

  // 3) causal attention -> y [N,C] bf16
  attn_kernel<<<dim3(Tc / 128, Bc * Hc), 512, 0, stream>>>(qb, kbuf, vbuf, ybuf);

  // 4) proj + residual -> d_out (f32)
  {
    GArgs p = {};
    p.A = ybuf; p.Bt = proj_wT; p.bias = proj_b;
    p.M = Nc; p.N = Cc; p.K = Cc; p.lda = Cc; p.ldb = Cc; p.klen = Cc;
    p.outF = out; p.resid = x;
    gemm128b<1><<<dim3(Cc / 128, Nc / 128, 1), 256, 0, stream>>>(p);
  }

  // 5) LN2 + router -> h (bf16), top-2
  ln2_router_kernel<<<Nc, 256, 0, stream>>>(out, ln2_g, ln2_b, router_w, h, tki, tkp);

  // 6) routing lists (slot-compacted pairs)
  hipMemsetAsync(counts, 0, Ec * sizeof(int), stream);
  count_kernel<<<(Nc + 255) / 256, 256, 0, stream>>>(tki, counts);
  scan_kernel<<<1, 64, 0, stream>>>(counts, eoff, cursor);
  assign_kernel<<<(Nc + 255) / 256, 256, 0, stream>>>(tki, cursor, slot_tok, tok2slot);

  // 7) fc -> he [NPAIR][HID] bf16 w/ GELU.
  //    1-D grid: id&7 = expert (==XCD); local = id>>3 = col*32 + rowblock.
  //    32 cols x 32 rowblock slots x 8 experts = 8192 blocks (dead slots exit).
  {
    GArgs f = {};
    f.A = h; f.Bt = fc_wT; f.bias = fc_b;
    f.M = Nc; f.N = HIDc; f.K = Cc; f.lda = Cc; f.ldb = Cc; f.klen = Cc;
    f.Bstride = (size_t)HIDc * Cc; f.biasStride = HIDc;
    f.eoff = eoff; f.slot_tok = slot_tok;
    f.outB = he;
    gemm128b<2><<<8 * 32 * 32, 256, 0, stream>>>(f);
  }

  // 8) pj split-K=2 -> pairout[kh][NPAIR][C] f32 (bias in kh=0).
  //    1-D grid: id&7 = expert; local = ((col*2+kh)*32 + rowblock).
  {
    GArgs pj = {};
    pj.A = he; pj.Bt = pj_wT; pj.bias = pj_b;
    pj.M = Nc; pj.N = Cc; pj.K = HIDc; pj.lda = HIDc; pj.ldb = HIDc; pj.klen = HIDc / 2;
    pj.Bstride = (size_t)Cc * HIDc; pj.biasStride = Cc;
    pj.eoff = eoff;
    pj.outF = pairout;
    gemm128b<3><<<8 * 16 * 32, 256, 0, stream>>>(pj);
  }

  // 9) deterministic combine into d_out
  combine_kernel<<<Nc, 256, 0, stream>>>(pairout, tkp, tok2slot, out);
}

// Round 12
// 673.028 us; speedup vs baseline: 1.0235x; 1.0235x over previous
//
#include <hip/hip_runtime.h>
#include <math.h>

// ---------------------------------------------------------------------------
// Fused transformer block w/ MoE (B=2,T=2048,C=1024,H=16,D=64,E=8,topK=2)
// Round 12: r8 GEMM restored (best measured: single-buf 128x128/BK=64,
// 32KiB LDS -> ~5 blocks/CU, XOR swizzle, exact MoE grids). New: attn
// heavy-first dispatch (qt reversed), pj+combine fused via f32 atomicAdd.
// ---------------------------------------------------------------------------

typedef __bf16 b16v8 __attribute__((ext_vector_type(8)));
typedef float f32x4 __attribute__((ext_vector_type(4)));

#define MFMA(a, b, c) __builtin_amdgcn_mfma_f32_16x16x32_bf16(a, b, c, 0, 0, 0)

#define GLOAD_LDS16(g, l)                                          \
  __builtin_amdgcn_global_load_lds(                                \
      (const __attribute__((address_space(1))) void*)(g),          \
      (__attribute__((address_space(3))) void*)(l), 16, 0, 0)

constexpr int Bc = 2, Tc = 2048, Cc = 1024, Hc = 16, Dc = 64;
constexpr int Nc = Bc * Tc;       // 4096 tokens
constexpr int HIDc = 4096;        // 4*C
constexpr int Ec = 8;
constexpr int NPAIR = Nc * 2;     // 8192
constexpr int NRBMAX = NPAIR / 128 + Ec;  // 72
constexpr float LOG2E = 1.4426950408889634f;

__device__ inline unsigned short f32_bf16(float f) {
  union { float f; unsigned u; } x; x.f = f;
  unsigned r = x.u + 0x7fffu + ((x.u >> 16) & 1u);   // RNE
  return (unsigned short)(r >> 16);
}

// gelu(x) = x * sigmoid(1.595769122*(x+0.044715x^3)); exp2-domain
__device__ inline float gelu_f(float x) {
  float t = 2.3021188f * x * (1.f + 0.044715f * x * x);
  float e = __builtin_amdgcn_exp2f(-t);
  return x * __builtin_amdgcn_rcpf(1.f + e);
}

// LDS element index for [row][64-elem] rows with 16B-granule XOR swizzle.
__device__ inline int swz(int row, int g) {
  return row * 64 + ((g ^ (row & 7)) * 8);
}

// ---------------------------------------------------------------------------
// Transpose+convert: src f32 [batch][K][N] -> dst bf16 [batch][N][K]
// ---------------------------------------------------------------------------
__global__ __launch_bounds__(256) void convT_kernel(
    const float* __restrict__ src, unsigned short* __restrict__ dst,
    int K, int N) {
  const size_t sb = (size_t)blockIdx.z * K * N;
  const int n0 = blockIdx.x * 32, k0 = blockIdx.y * 32;
  __shared__ float t[32][33];
  const int tx = threadIdx.x & 31, ty = threadIdx.x >> 5;
#pragma unroll
  for (int j = 0; j < 4; ++j)
    t[ty + j * 8][tx] = src[sb + (size_t)(k0 + ty + j * 8) * N + n0 + tx];
  __syncthreads();
#pragma unroll
  for (int j = 0; j < 4; ++j)
    dst[sb + (size_t)(n0 + ty + j * 8) * K + k0 + tx] = f32_bf16(t[tx][ty + j * 8]);
}

// ---------------------------------------------------------------------------
// LayerNorm (f32 in -> bf16 out).
// ---------------------------------------------------------------------------
__global__ __launch_bounds__(256) void ln1_kernel(
    const float* __restrict__ x, const float* __restrict__ g,
    const float* __restrict__ b, unsigned short* __restrict__ out) {
  const int row = blockIdx.x;
  const int tid = threadIdx.x;
  const float* xr = x + (size_t)row * Cc;
  float v[4]; float s = 0.f, q = 0.f;
#pragma unroll
  for (int j = 0; j < 4; ++j) { v[j] = xr[tid + j * 256]; s += v[j]; q += v[j] * v[j]; }
#pragma unroll
  for (int m = 1; m <= 32; m <<= 1) { s += __shfl_xor(s, m); q += __shfl_xor(q, m); }
  __shared__ float red[2][4];
  const int w = tid >> 6;
  if ((tid & 63) == 0) { red[0][w] = s; red[1][w] = q; }
  __syncthreads();
  s = red[0][0] + red[0][1] + red[0][2] + red[0][3];
  q = red[1][0] + red[1][1] + red[1][2] + red[1][3];
  const float mean = s * (1.f / Cc);
  const float var = q * (1.f / Cc) - mean * mean;
  const float rstd = rsqrtf(var + 1e-5f);
#pragma unroll
  for (int j = 0; j < 4; ++j) {
    int c = tid + j * 256;
    out[(size_t)row * Cc + c] = f32_bf16((v[j] - mean) * rstd * g[c] + b[c]);
  }
}

// ---------------------------------------------------------------------------
// LN2 + router (f32 router math).
// ---------------------------------------------------------------------------
__global__ __launch_bounds__(256) void ln2_router_kernel(
    const float* __restrict__ x, const float* __restrict__ g,
    const float* __restrict__ b, const float* __restrict__ rw,
    unsigned short* __restrict__ out, int* __restrict__ tki, float* __restrict__ tkp) {
  const int row = blockIdx.x;
  const int tid = threadIdx.x;
  const float* xr = x + (size_t)row * Cc;
  float v[4]; float s = 0.f, q = 0.f;
#pragma unroll
  for (int j = 0; j < 4; ++j) { v[j] = xr[tid + j * 256]; s += v[j]; q += v[j] * v[j]; }
#pragma unroll
  for (int m = 1; m <= 32; m <<= 1) { s += __shfl_xor(s, m); q += __shfl_xor(q, m); }
  __shared__ float red[2][4];
  const int w = tid >> 6;
  if ((tid & 63) == 0) { red[0][w] = s; red[1][w] = q; }
  __syncthreads();
  s = red[0][0] + red[0][1] + red[0][2] + red[0][3];
  q = red[1][0] + red[1][1] + red[1][2] + red[1][3];
  const float mean = s * (1.f / Cc);
  const float var = q * (1.f / Cc) - mean * mean;
  const float rstd = rsqrtf(var + 1e-5f);
  float lg[8] = {0.f, 0.f, 0.f, 0.f, 0.f, 0.f, 0.f, 0.f};
#pragma unroll
  for (int j = 0; j < 4; ++j) {
    int c = tid + j * 256;
    float nv = (v[j] - mean) * rstd * g[c] + b[c];
    out[(size_t)row * Cc + c] = f32_bf16(nv);
    const float* rwc = rw + c * 8;
#pragma unroll
    for (int e = 0; e < 8; ++e) lg[e] += nv * rwc[e];
  }
#pragma unroll
  for (int m = 1; m <= 32; m <<= 1) {
#pragma unroll
    for (int e = 0; e < 8; ++e) lg[e] += __shfl_xor(lg[e], m);
  }
  __shared__ float rl[4][8];
  if ((tid & 63) == 0) {
#pragma unroll
    for (int e = 0; e < 8; ++e) rl[w][e] = lg[e];
  }
  __syncthreads();
  if (tid == 0) {
    float L[8];
#pragma unroll
    for (int e = 0; e < 8; ++e) L[e] = rl[0][e] + rl[1][e] + rl[2][e] + rl[3][e];
    int i1 = 0;
    for (int e = 1; e < 8; ++e) if (L[e] > L[i1]) i1 = e;
    int i2 = (i1 == 0) ? 1 : 0;
    for (int e = 0; e < 8; ++e) if (e != i1 && L[e] > L[i2]) i2 = e;
    float e2 = expf(L[i2] - L[i1]);
    float inv = 1.f / (1.f + e2);
    tki[row * 2] = i1; tki[row * 2 + 1] = i2;
    tkp[row * 2] = inv; tkp[row * 2 + 1] = e2 * inv;
  }
}

// ---------------------------------------------------------------------------
// Routing: counts -> offsets + rowblock table -> slot assignment.
// ---------------------------------------------------------------------------
__global__ __launch_bounds__(256) void count_kernel(
    const int* __restrict__ tki, int* __restrict__ counts) {
  int n = blockIdx.x * 256 + threadIdx.x;
  if (n >= Nc) return;
  atomicAdd(&counts[tki[n * 2]], 1);
  atomicAdd(&counts[tki[n * 2 + 1]], 1);
}

__global__ void scan_kernel(const int* __restrict__ counts,
                            int* __restrict__ eoff, int* __restrict__ cursor,
                            int* __restrict__ tbl_e, int* __restrict__ tbl_r0,
                            int* __restrict__ tbl_n) {
  if (threadIdx.x == 0 && blockIdx.x == 0) {
    int s = 0, nb = 0;
    for (int e = 0; e < Ec; ++e) {
      eoff[e] = s; cursor[e] = s;
      for (int r = 0; r < counts[e]; r += 128) {
        tbl_e[nb] = e; tbl_r0[nb] = r; ++nb;
      }
      s += counts[e];
    }
    eoff[Ec] = s;
    *tbl_n = nb;
  }
}

__global__ __launch_bounds__(256) void assign_kernel(
    const int* __restrict__ tki, const float* __restrict__ tkp,
    int* __restrict__ cursor, int* __restrict__ slot_tok,
    float* __restrict__ slot_gate) {
  int n = blockIdx.x * 256 + threadIdx.x;
  if (n >= Nc) return;
#pragma unroll
  for (int kk = 0; kk < 2; ++kk) {
    int e = tki[n * 2 + kk];
    int slot = atomicAdd(&cursor[e], 1);
    slot_tok[slot] = n;
    slot_gate[slot] = tkp[n * 2 + kk];
  }
}

// ---------------------------------------------------------------------------
struct GArgs {
  const unsigned short* A;    // bf16 [M][lda]
  const unsigned short* Bt;   // bf16 [N][ldb] (+ e*Bstride)
  const float* bias;          // f32 [N]      (+ e*biasStride)
  int M, N, K, lda, ldb, klen;
  size_t Bstride; int biasStride;
  const int* eoff;            // [E+1] (MODE 2/3)
  const int* slot_tok;        // (MODE 2/3)
  const float* slot_gate;     // (MODE 3)
  const int* tbl_e;           // rowblock table (MODE 2/3)
  const int* tbl_r0;
  const int* tbl_n;
  float* outF;                // MODE 1: out, MODE 3: out (atomic)
  const float* resid;         // MODE 1
  unsigned short* outB;       // MODE 2: he ; MODE 0: q
  unsigned short* outK;       // MODE 0: k
  unsigned short* outV;       // MODE 0: v^T [B,H,D,T]
};

// ---------------------------------------------------------------------------
// 128x128 tile, BK=64, 4 waves (2x2), SINGLE buffer, XOR granule swizzle.
// 32 KiB LDS -> ~5 blocks/CU; cross-block TLP hides stage drains (r8 best).
// MODE: 0=QKV scatter, 1=proj+resid, 2=fc gather+gelu,
//       3=pj split-K (z=kh) * gate -> atomicAdd(out)
// ---------------------------------------------------------------------------
template <int MODE>
__global__ __launch_bounds__(256) void gemm128b(GArgs g) {
  int e = 0, s0 = 0, Meff = g.M, row0;
  if constexpr (MODE == 2 || MODE == 3) {
    if ((int)blockIdx.y >= *g.tbl_n) return;
    e = g.tbl_e[blockIdx.y];
    row0 = g.tbl_r0[blockIdx.y];
    s0 = g.eoff[e];
    Meff = g.eoff[e + 1] - s0;
  } else {
    row0 = blockIdx.y * 128;
  }
  const int kh = (MODE == 3) ? blockIdx.z : 0;
  const int col0 = blockIdx.x * 128;
  const int kbase = kh * g.klen;

  __shared__ __align__(16) unsigned short As[128 * 64];
  __shared__ __align__(16) unsigned short Bs[128 * 64];

  const int tid = threadIdx.x;
  const int lane = tid & 63, w = tid >> 6;
  const int wr = w >> 1, wc = w & 1;
  const int fr = lane & 15, fg = lane >> 4;

  const unsigned short* Bt = g.Bt + (size_t)e * g.Bstride;
  const float* bias = g.bias + (size_t)e * g.biasStride;

  // LDS dest linear (gload_lds); GLOBAL source granule pre-swizzled (#21).
  size_t aaddr[4], baddr[4];
#pragma unroll
  for (int i = 0; i < 4; ++i) {
    int pos = i * 256 + tid;                   // 16B-granule index 0..1023
    int r = pos >> 3;                          // LDS row 0..127
    int c8 = ((pos & 7) ^ (r & 7)) * 8;        // swizzled source (elems)
    int gr = row0 + r;
    if (gr >= Meff) gr = Meff - 1;
    int srcrow;
    if constexpr (MODE == 2) srcrow = g.slot_tok[s0 + gr];
    else if constexpr (MODE == 3) srcrow = s0 + gr;
    else srcrow = gr;
    aaddr[i] = (size_t)srcrow * g.lda + kbase + c8;
    baddr[i] = (size_t)(col0 + r) * g.ldb + kbase + c8;
  }

  auto STAGE = [&](int k0) {
#pragma unroll
    for (int i = 0; i < 4; ++i) {
      GLOAD_LDS16(g.A + aaddr[i] + k0, &As[i * 2048 + w * 512]);
      GLOAD_LDS16(Bt + baddr[i] + k0, &Bs[i * 2048 + w * 512]);
    }
  };

  f32x4 acc[4][4] = {};
  const int nt = g.klen / 64;

  for (int t = 0; t < nt; ++t) {
    if (t) __syncthreads();                 // reads of prev tile complete
    STAGE(t * 64);
    __syncthreads();                        // stage-writes landed (vmcnt drain)
    b16v8 af[4][2], bf_[4][2];
#pragma unroll
    for (int mi = 0; mi < 4; ++mi) {
      const int ar = wr * 64 + mi * 16 + fr;
      af[mi][0] = *(const b16v8*)&As[swz(ar, fg)];
      af[mi][1] = *(const b16v8*)&As[swz(ar, 4 + fg)];
    }
#pragma unroll
    for (int ni = 0; ni < 4; ++ni) {
      const int br = wc * 64 + ni * 16 + fr;
      bf_[ni][0] = *(const b16v8*)&Bs[swz(br, fg)];
      bf_[ni][1] = *(const b16v8*)&Bs[swz(br, 4 + fg)];
    }
#pragma unroll
    for (int mi = 0; mi < 4; ++mi)
#pragma unroll
      for (int ni = 0; ni < 4; ++ni) {
        acc[mi][ni] = MFMA(af[mi][0], bf_[ni][0], acc[mi][ni]);
        acc[mi][ni] = MFMA(af[mi][1], bf_[ni][1], acc[mi][ni]);
      }
  }

#pragma unroll
  for (int mi = 0; mi < 4; ++mi) {
#pragma unroll
    for (int ni = 0; ni < 4; ++ni) {
#pragma unroll
      for (int rr = 0; rr < 4; ++rr) {
        int row = row0 + wr * 64 + mi * 16 + fg * 4 + rr;
        int col = col0 + wc * 64 + ni * 16 + fr;
        if (row >= Meff) continue;
        float bval = bias[col];
        if constexpr (MODE == 3) { if (kh != 0) bval = 0.f; }
        float val = acc[mi][ni][rr] + bval;
        if constexpr (MODE == 0) {
          int bb = row >> 11, tt = row & (Tc - 1);
          int which = col >> 10, cj = col & (Cc - 1);
          int hd = cj >> 6, d = cj & 63;
          if (which == 0)
            g.outB[(((size_t)(bb * Hc + hd)) * Tc + tt) * Dc + d] = f32_bf16(val);
          else if (which == 1)
            g.outK[(((size_t)(bb * Hc + hd)) * Tc + tt) * Dc + d] = f32_bf16(val);
          else
            g.outV[(((size_t)(bb * Hc + hd)) * Dc + d) * Tc + tt] = f32_bf16(val);
        } else if constexpr (MODE == 1) {
          size_t o = (size_t)row * g.N + col;
          g.outF[o] = val + g.resid[o];
        } else if constexpr (MODE == 2) {
          g.outB[(size_t)(s0 + row) * g.N + col] = f32_bf16(gelu_f(val));
        } else {
          int tok = g.slot_tok[s0 + row];
          atomicAdd(&g.outF[(size_t)tok * Cc + col],
                    g.slot_gate[s0 + row] * val);
        }
      }
    }
  }
}

// ---------------------------------------------------------------------------
// Flash-style causal attention. 8 waves, 128 q-rows, KV tile 64.
// Heavy-first dispatch: qt reversed so the longest (most kv-tiles) blocks
// start first and light blocks backfill CU slots.
// T14 async-stage: next K/V tile global->reg issued before compute.
// ---------------------------------------------------------------------------
__global__ __launch_bounds__(512) void attn_kernel(
    const unsigned short* __restrict__ q, const unsigned short* __restrict__ k,
    const unsigned short* __restrict__ v, unsigned short* __restrict__ y) {
  const int qt = gridDim.x - 1 - blockIdx.x;   // heavy-first
  const int bh = blockIdx.y;
  const int qbase = qt * 128;
  __shared__ __align__(16) unsigned short ldsK[64][72];
  __shared__ __align__(16) unsigned short ldsVT[64][72];     // [d][kv]
  __shared__ __align__(16) unsigned short ldsP[8][16][72];
  const int tid = threadIdx.x, lane = tid & 63, w = tid >> 6;
  const int fr = lane & 15, fg = lane >> 4;
  const size_t base = (size_t)bh * Tc * Dc;
  const int qrow = qbase + w * 16 + fr;
  b16v8 qa0 = *(const b16v8*)(q + base + (size_t)qrow * Dc + fg * 8);
  b16v8 qa1 = *(const b16v8*)(q + base + (size_t)qrow * Dc + 32 + fg * 8);
  float m[4], lsum[4] = {0.f, 0.f, 0.f, 0.f};
#pragma unroll
  for (int r = 0; r < 4; ++r) m[r] = -3.0e38f;
  f32x4 oacc[4] = {};
  constexpr float SC = 0.125f * LOG2E;

  const int sr = tid >> 3, scb = (tid & 7) * 8;
  const int ntile = (qbase + 128) / 64;

  *(uint4*)&ldsK[sr][scb]  = *(const uint4*)(k + base + (size_t)sr * Dc + scb);
  *(uint4*)&ldsVT[sr][scb] = *(const uint4*)(v + base + (size_t)sr * Tc + scb);
  __syncthreads();

  for (int ti = 0; ti < ntile; ++ti) {
    const int kb = ti * 64;
    uint4 kreg, vreg;
    const bool more = (ti + 1 < ntile);
    if (more) {
      const int kn = kb + 64;
      kreg = *(const uint4*)(k + base + (size_t)(kn + sr) * Dc + scb);
      vreg = *(const uint4*)(v + base + (size_t)sr * Tc + kn + scb);
    }

    f32x4 s[4];
#pragma unroll
    for (int ni = 0; ni < 4; ++ni) {
      b16v8 kb0 = *(const b16v8*)&ldsK[ni * 16 + fr][fg * 8];
      b16v8 kb1 = *(const b16v8*)&ldsK[ni * 16 + fr][32 + fg * 8];
      f32x4 z = {};
      z = MFMA(qa0, kb0, z);
      z = MFMA(qa1, kb1, z);
      s[ni] = z;
    }
    const bool diag = (kb + 64 > qbase + w * 16);
#pragma unroll
    for (int ni = 0; ni < 4; ++ni) {
#pragma unroll
      for (int r = 0; r < 4; ++r) {
        float sv = s[ni][r] * SC;
        if (diag) {
          int gq = qbase + w * 16 + fg * 4 + r;
          int kv = kb + ni * 16 + fr;
          if (kv > gq) sv = -3.0e38f;
        }
        s[ni][r] = sv;
      }
    }
#pragma unroll
    for (int r = 0; r < 4; ++r) {
      float mx = fmaxf(fmaxf(s[0][r], s[1][r]), fmaxf(s[2][r], s[3][r]));
#pragma unroll
      for (int msk = 1; msk <= 8; msk <<= 1) mx = fmaxf(mx, __shfl_xor(mx, msk));
      float mnew = fmaxf(m[r], mx);
      float alpha = __builtin_amdgcn_exp2f(m[r] - mnew);
      float psum = 0.f;
#pragma unroll
      for (int ni = 0; ni < 4; ++ni) {
        float pp = __builtin_amdgcn_exp2f(s[ni][r] - mnew);
        s[ni][r] = pp;
        psum += pp;
      }
#pragma unroll
      for (int msk = 1; msk <= 8; msk <<= 1) psum += __shfl_xor(psum, msk);
      lsum[r] = lsum[r] * alpha + psum;
      m[r] = mnew;
#pragma unroll
      for (int ni = 0; ni < 4; ++ni) {
        oacc[ni][r] = oacc[ni][r] * alpha;
        ldsP[w][fg * 4 + r][ni * 16 + fr] = f32_bf16(s[ni][r]);
      }
    }
    asm volatile("s_waitcnt lgkmcnt(0)" ::: "memory");
    __builtin_amdgcn_sched_barrier(0);
    b16v8 pa0 = *(const b16v8*)&ldsP[w][fr][fg * 8];
    b16v8 pa1 = *(const b16v8*)&ldsP[w][fr][32 + fg * 8];
#pragma unroll
    for (int ni = 0; ni < 4; ++ni) {
      b16v8 vb0 = *(const b16v8*)&ldsVT[ni * 16 + fr][fg * 8];
      b16v8 vb1 = *(const b16v8*)&ldsVT[ni * 16 + fr][32 + fg * 8];
      oacc[ni] = MFMA(pa0, vb0, oacc[ni]);
      oacc[ni] = MFMA(pa1, vb1, oacc[ni]);
    }

    if (more) {
      __syncthreads();
      *(uint4*)&ldsK[sr][scb]  = kreg;
      *(uint4*)&ldsVT[sr][scb] = vreg;
      __syncthreads();
    }
  }

  const int bb = bh >> 4, hh = bh & 15;
#pragma unroll
  for (int r = 0; r < 4; ++r) {
    float rl = __builtin_amdgcn_rcpf(lsum[r]);
#pragma unroll
    for (int ni = 0; ni < 4; ++ni) {
      int t = qbase + w * 16 + fg * 4 + r;
      int d = ni * 16 + fr;
      y[((size_t)(bb * Tc + t)) * Cc + hh * Dc + d] = f32_bf16(oacc[ni][r] * rl);
    }
  }
}

// ---------------------------------------------------------------------------
extern "C" void kernel_launch(void* const* d_in, const int* in_sizes, int n_in,
                              void* d_out, int out_size, void* d_ws, size_t ws_size,
                              hipStream_t stream) {
  const float* x        = (const float*)d_in[0];
  const float* ln1_g    = (const float*)d_in[1];
  const float* ln1_b    = (const float*)d_in[2];
  const float* ln2_g    = (const float*)d_in[3];
  const float* ln2_b    = (const float*)d_in[4];
  const float* attn_w   = (const float*)d_in[5];
  const float* attn_b   = (const float*)d_in[6];
  const float* proj_w   = (const float*)d_in[7];
  const float* proj_b   = (const float*)d_in[8];
  const float* router_w = (const float*)d_in[9];
  const float* fc_w     = (const float*)d_in[10];
  const float* fc_b     = (const float*)d_in[11];
  const float* pj_w     = (const float*)d_in[12];
  const float* pj_b     = (const float*)d_in[13];
  float* out = (float*)d_out;

  char* ws = (char*)d_ws;
  size_t off = 0;
  auto alloc = [&](size_t bytes) -> void* {
    void* p = ws + off;
    off = (off + bytes + 255) & ~(size_t)255;
    return p;
  };
  unsigned short* attn_wT = (unsigned short*)alloc((size_t)3 * Cc * Cc * 2);
  unsigned short* proj_wT = (unsigned short*)alloc((size_t)Cc * Cc * 2);
  unsigned short* fc_wT   = (unsigned short*)alloc((size_t)Ec * HIDc * Cc * 2);
  unsigned short* pj_wT   = (unsigned short*)alloc((size_t)Ec * Cc * HIDc * 2);
  unsigned short* h    = (unsigned short*)alloc((size_t)Nc * Cc * 2);
  unsigned short* qb   = (unsigned short*)alloc((size_t)Nc * Cc * 2);   // [B,H,T,D]
  unsigned short* kbuf = (unsigned short*)alloc((size_t)Nc * Cc * 2);   // [B,H,T,D]
  unsigned short* vbuf = (unsigned short*)alloc((size_t)Nc * Cc * 2);   // [B,H,D,T]
  unsigned short* ybuf = (unsigned short*)alloc((size_t)Nc * Cc * 2);   // [N,C]
  unsigned short* he   = (unsigned short*)alloc((size_t)NPAIR * HIDc * 2);
  int*   tki      = (int*)alloc((size_t)Nc * 2 * 4);
  float* tkp      = (float*)alloc((size_t)Nc * 2 * 4);
  int*   counts   = (int*)alloc(Ec * 4);
  int*   eoff     = (int*)alloc((Ec + 1) * 4);
  int*   cursor   = (int*)alloc(Ec * 4);
  int*   slot_tok = (int*)alloc((size_t)NPAIR * 4);
  float* slot_gate= (float*)alloc((size_t)NPAIR * 4);
  int*   tbl_e    = (int*)alloc(NRBMAX * 4);
  int*   tbl_r0   = (int*)alloc(NRBMAX * 4);
  int*   tbl_n    = (int*)alloc(4);
  (void)ws_size; (void)in_sizes; (void)n_in; (void)out_size;

  // 0) weight pre-transpose/convert
  convT_kernel<<<dim3(3 * Cc / 32, Cc / 32, 1), 256, 0, stream>>>(attn_w, attn_wT, Cc, 3 * Cc);
  convT_kernel<<<dim3(Cc / 32, Cc / 32, 1), 256, 0, stream>>>(proj_w, proj_wT, Cc, Cc);
  convT_kernel<<<dim3(HIDc / 32, Cc / 32, Ec), 256, 0, stream>>>(fc_w, fc_wT, Cc, HIDc);
  convT_kernel<<<dim3(Cc / 32, HIDc / 32, Ec), 256, 0, stream>>>(pj_w, pj_wT, HIDc, Cc);

  // 1) LN1
  ln1_kernel<<<Nc, 256, 0, stream>>>(x, ln1_g, ln1_b, h);

  // 2) QKV GEMM -> q/k [B,H,T,D], v^T [B,H,D,T]
  {
    GArgs a = {};
    a.A = h; a.Bt = attn_wT; a.bias = attn_b;
    a.M = Nc; a.N = 3 * Cc; a.K = Cc; a.lda = Cc; a.ldb = Cc; a.klen = Cc;
    a.outB = qb; a.outK = kbuf; a.outV = vbuf;
    gemm128b<0><<<dim3(3 * Cc / 128, Nc / 128, 1), 256, 0, stream>>>(a);
  }

  // 3) causal attention -> y [N,C] bf16 (heavy-first)
  attn_kernel<<<dim3(Tc / 128, Bc * Hc), 512, 0, stream>>>(qb, kbuf, vbuf, ybuf);

  // 4) proj + residual -> d_out (f32)
  {
    GArgs p = {};
    p.A = ybuf; p.Bt = proj_wT; p.bias = proj_b;
    p.M = Nc; p.N = Cc; p.K = Cc; p.lda = Cc; p.ldb = Cc; p.klen = Cc;
    p.outF = out; p.resid = x;
    gemm128b<1><<<dim3(Cc / 128, Nc / 128, 1), 256, 0, stream>>>(p);
  }

  // 5) LN2 + router -> h (bf16), top-2
  ln2_router_kernel<<<Nc, 256, 0, stream>>>(out, ln2_g, ln2_b, router_w, h, tki, tkp);

  // 6) routing lists (slot-compacted pairs) + rowblock table
  hipMemsetAsync(counts, 0, Ec * sizeof(int), stream);
  count_kernel<<<(Nc + 255) / 256, 256, 0, stream>>>(tki, counts);
  scan_kernel<<<1, 64, 0, stream>>>(counts, eoff, cursor, tbl_e, tbl_r0, tbl_n);
  assign_kernel<<<(Nc + 255) / 256, 256, 0, stream>>>(tki, tkp, cursor, slot_tok, slot_gate);

  // 7) fc -> he [NPAIR][HID] bf16 w/ GELU (exact rowblock grid)
  {
    GArgs f = {};
    f.A = h; f.Bt = fc_wT; f.bias = fc_b;
    f.M = Nc; f.N = HIDc; f.K = Cc; f.lda = Cc; f.ldb = Cc; f.klen = Cc;
    f.Bstride = (size_t)HIDc * Cc; f.biasStride = HIDc;
    f.eoff = eoff; f.slot_tok = slot_tok;
    f.tbl_e = tbl_e; f.tbl_r0 = tbl_r0; f.tbl_n = tbl_n;
    f.outB = he;
    gemm128b<2><<<dim3(HIDc / 128, NRBMAX, 1), 256, 0, stream>>>(f);
  }

  // 8) pj split-K=2, gate-weighted atomicAdd into d_out (bias in kh=0)
  {
    GArgs pj = {};
    pj.A = he; pj.Bt = pj_wT; pj.bias = pj_b;
    pj.M = Nc; pj.N = Cc; pj.K = HIDc; pj.lda = HIDc; pj.ldb = HIDc; pj.klen = HIDc / 2;
    pj.Bstride = (size_t)Cc * HIDc; pj.biasStride = Cc;
    pj.eoff = eoff; pj.slot_tok = slot_tok; pj.slot_gate = slot_gate;
    pj.tbl_e = tbl_e; pj.tbl_r0 = tbl_r0; pj.tbl_n = tbl_n;
    pj.outF = out;
    gemm128b<3><<<dim3(Cc / 128, NRBMAX, 2), 256, 0, stream>>>(pj);
  }
}

// Round 13
// 616.548 us; speedup vs baseline: 1.1173x; 1.0916x over previous
//
#include <hip/hip_runtime.h>
#include <math.h>

// ---------------------------------------------------------------------------
// Fused transformer block w/ MoE (B=2,T=2048,C=1024,H=16,D=64,E=8,topK=2)
// Round 13: r8 GEMM (single-buf 128x128/BK=64, 32KiB LDS, ~5 blocks/CU,
// XOR swizzle, exact MoE grids) + pairout/combine epilogue (atomics reverted),
// pj single-K (no split), fast convT (float4/ushort4), heavy-first attn.
// ---------------------------------------------------------------------------

typedef __bf16 b16v8 __attribute__((ext_vector_type(8)));
typedef float f32x4 __attribute__((ext_vector_type(4)));

#define MFMA(a, b, c) __builtin_amdgcn_mfma_f32_16x16x32_bf16(a, b, c, 0, 0, 0)

#define GLOAD_LDS16(g, l)                                          \
  __builtin_amdgcn_global_load_lds(                                \
      (const __attribute__((address_space(1))) void*)(g),          \
      (__attribute__((address_space(3))) void*)(l), 16, 0, 0)

constexpr int Bc = 2, Tc = 2048, Cc = 1024, Hc = 16, Dc = 64;
constexpr int Nc = Bc * Tc;       // 4096 tokens
constexpr int HIDc = 4096;        // 4*C
constexpr int Ec = 8;
constexpr int NPAIR = Nc * 2;     // 8192
constexpr int NRBMAX = NPAIR / 128 + Ec;  // 72
constexpr float LOG2E = 1.4426950408889634f;

__device__ inline unsigned short f32_bf16(float f) {
  union { float f; unsigned u; } x; x.f = f;
  unsigned r = x.u + 0x7fffu + ((x.u >> 16) & 1u);   // RNE
  return (unsigned short)(r >> 16);
}

// gelu(x) = x * sigmoid(1.595769122*(x+0.044715x^3)); exp2-domain
__device__ inline float gelu_f(float x) {
  float t = 2.3021188f * x * (1.f + 0.044715f * x * x);
  float e = __builtin_amdgcn_exp2f(-t);
  return x * __builtin_amdgcn_rcpf(1.f + e);
}

// LDS element index for [row][64-elem] rows with 16B-granule XOR swizzle.
__device__ inline int swz(int row, int g) {
  return row * 64 + ((g ^ (row & 7)) * 8);
}

// ---------------------------------------------------------------------------
// Transpose+convert: src f32 [batch][K][N] -> dst bf16 [batch][N][K]
// 64x64 tile, float4 reads, LDS [64][65] (2-way bank = free), ushort4 writes.
// ---------------------------------------------------------------------------
__global__ __launch_bounds__(256) void convT_kernel(
    const float* __restrict__ src, unsigned short* __restrict__ dst,
    int K, int N) {
  const size_t sb = (size_t)blockIdx.z * K * N;
  const int n0 = blockIdx.x * 64, k0 = blockIdx.y * 64;
  __shared__ float t[64][65];
  const int tid = threadIdx.x;
#pragma unroll
  for (int j = 0; j < 4; ++j) {
    int idx = j * 256 + tid;            // 0..1023
    int r = idx >> 4;                   // k-row 0..63
    int c4 = (idx & 15) << 2;           // n-col 0..60 step 4
    float4 v = *(const float4*)&src[sb + (size_t)(k0 + r) * N + n0 + c4];
    t[r][c4] = v.x; t[r][c4 + 1] = v.y; t[r][c4 + 2] = v.z; t[r][c4 + 3] = v.w;
  }
  __syncthreads();
#pragma unroll
  for (int j = 0; j < 4; ++j) {
    int idx = j * 256 + tid;
    int n = idx >> 4;                   // n-row 0..63
    int k4 = (idx & 15) << 2;           // k-col 0..60 step 4
    ushort4 o;
    o.x = f32_bf16(t[k4][n]);
    o.y = f32_bf16(t[k4 + 1][n]);
    o.z = f32_bf16(t[k4 + 2][n]);
    o.w = f32_bf16(t[k4 + 3][n]);
    *(ushort4*)&dst[sb + (size_t)(n0 + n) * K + k0 + k4] = o;
  }
}

// ---------------------------------------------------------------------------
// LayerNorm (f32 in -> bf16 out).
// ---------------------------------------------------------------------------
__global__ __launch_bounds__(256) void ln1_kernel(
    const float* __restrict__ x, const float* __restrict__ g,
    const float* __restrict__ b, unsigned short* __restrict__ out) {
  const int row = blockIdx.x;
  const int tid = threadIdx.x;
  const float* xr = x + (size_t)row * Cc;
  float v[4]; float s = 0.f, q = 0.f;
#pragma unroll
  for (int j = 0; j < 4; ++j) { v[j] = xr[tid + j * 256]; s += v[j]; q += v[j] * v[j]; }
#pragma unroll
  for (int m = 1; m <= 32; m <<= 1) { s += __shfl_xor(s, m); q += __shfl_xor(q, m); }
  __shared__ float red[2][4];
  const int w = tid >> 6;
  if ((tid & 63) == 0) { red[0][w] = s; red[1][w] = q; }
  __syncthreads();
  s = red[0][0] + red[0][1] + red[0][2] + red[0][3];
  q = red[1][0] + red[1][1] + red[1][2] + red[1][3];
  const float mean = s * (1.f / Cc);
  const float var = q * (1.f / Cc) - mean * mean;
  const float rstd = rsqrtf(var + 1e-5f);
#pragma unroll
  for (int j = 0; j < 4; ++j) {
    int c = tid + j * 256;
    out[(size_t)row * Cc + c] = f32_bf16((v[j] - mean) * rstd * g[c] + b[c]);
  }
}

// ---------------------------------------------------------------------------
// LN2 + router (f32 router math).
// ---------------------------------------------------------------------------
__global__ __launch_bounds__(256) void ln2_router_kernel(
    const float* __restrict__ x, const float* __restrict__ g,
    const float* __restrict__ b, const float* __restrict__ rw,
    unsigned short* __restrict__ out, int* __restrict__ tki, float* __restrict__ tkp) {
  const int row = blockIdx.x;
  const int tid = threadIdx.x;
  const float* xr = x + (size_t)row * Cc;
  float v[4]; float s = 0.f, q = 0.f;
#pragma unroll
  for (int j = 0; j < 4; ++j) { v[j] = xr[tid + j * 256]; s += v[j]; q += v[j] * v[j]; }
#pragma unroll
  for (int m = 1; m <= 32; m <<= 1) { s += __shfl_xor(s, m); q += __shfl_xor(q, m); }
  __shared__ float red[2][4];
  const int w = tid >> 6;
  if ((tid & 63) == 0) { red[0][w] = s; red[1][w] = q; }
  __syncthreads();
  s = red[0][0] + red[0][1] + red[0][2] + red[0][3];
  q = red[1][0] + red[1][1] + red[1][2] + red[1][3];
  const float mean = s * (1.f / Cc);
  const float var = q * (1.f / Cc) - mean * mean;
  const float rstd = rsqrtf(var + 1e-5f);
  float lg[8] = {0.f, 0.f, 0.f, 0.f, 0.f, 0.f, 0.f, 0.f};
#pragma unroll
  for (int j = 0; j < 4; ++j) {
    int c = tid + j * 256;
    float nv = (v[j] - mean) * rstd * g[c] + b[c];
    out[(size_t)row * Cc + c] = f32_bf16(nv);
    const float* rwc = rw + c * 8;
#pragma unroll
    for (int e = 0; e < 8; ++e) lg[e] += nv * rwc[e];
  }
#pragma unroll
  for (int m = 1; m <= 32; m <<= 1) {
#pragma unroll
    for (int e = 0; e < 8; ++e) lg[e] += __shfl_xor(lg[e], m);
  }
  __shared__ float rl[4][8];
  if ((tid & 63) == 0) {
#pragma unroll
    for (int e = 0; e < 8; ++e) rl[w][e] = lg[e];
  }
  __syncthreads();
  if (tid == 0) {
    float L[8];
#pragma unroll
    for (int e = 0; e < 8; ++e) L[e] = rl[0][e] + rl[1][e] + rl[2][e] + rl[3][e];
    int i1 = 0;
    for (int e = 1; e < 8; ++e) if (L[e] > L[i1]) i1 = e;
    int i2 = (i1 == 0) ? 1 : 0;
    for (int e = 0; e < 8; ++e) if (e != i1 && L[e] > L[i2]) i2 = e;
    float e2 = expf(L[i2] - L[i1]);
    float inv = 1.f / (1.f + e2);
    tki[row * 2] = i1; tki[row * 2 + 1] = i2;
    tkp[row * 2] = inv; tkp[row * 2 + 1] = e2 * inv;
  }
}

// ---------------------------------------------------------------------------
// Routing: counts -> offsets + rowblock table -> slot assignment.
// ---------------------------------------------------------------------------
__global__ __launch_bounds__(256) void count_kernel(
    const int* __restrict__ tki, int* __restrict__ counts) {
  int n = blockIdx.x * 256 + threadIdx.x;
  if (n >= Nc) return;
  atomicAdd(&counts[tki[n * 2]], 1);
  atomicAdd(&counts[tki[n * 2 + 1]], 1);
}

__global__ void scan_kernel(const int* __restrict__ counts,
                            int* __restrict__ eoff, int* __restrict__ cursor,
                            int* __restrict__ tbl_e, int* __restrict__ tbl_r0,
                            int* __restrict__ tbl_n) {
  if (threadIdx.x == 0 && blockIdx.x == 0) {
    int s = 0, nb = 0;
    for (int e = 0; e < Ec; ++e) {
      eoff[e] = s; cursor[e] = s;
      for (int r = 0; r < counts[e]; r += 128) {
        tbl_e[nb] = e; tbl_r0[nb] = r; ++nb;
      }
      s += counts[e];
    }
    eoff[Ec] = s;
    *tbl_n = nb;
  }
}

__global__ __launch_bounds__(256) void assign_kernel(
    const int* __restrict__ tki, int* __restrict__ cursor,
    int* __restrict__ slot_tok, int* __restrict__ tok2slot) {
  int n = blockIdx.x * 256 + threadIdx.x;
  if (n >= Nc) return;
#pragma unroll
  for (int kk = 0; kk < 2; ++kk) {
    int e = tki[n * 2 + kk];
    int slot = atomicAdd(&cursor[e], 1);
    slot_tok[slot] = n;
    tok2slot[n * 2 + kk] = slot;
  }
}

// ---------------------------------------------------------------------------
struct GArgs {
  const unsigned short* A;    // bf16 [M][lda]
  const unsigned short* Bt;   // bf16 [N][ldb] (+ e*Bstride)
  const float* bias;          // f32 [N]      (+ e*biasStride)
  int M, N, K, lda, ldb, klen;
  size_t Bstride; int biasStride;
  const int* eoff;            // [E+1] (MODE 2/3)
  const int* slot_tok;        // (MODE 2)
  const int* tbl_e;           // rowblock table (MODE 2/3)
  const int* tbl_r0;
  const int* tbl_n;
  float* outF;                // MODE 1: out, MODE 3: pairout
  const float* resid;         // MODE 1
  unsigned short* outB;       // MODE 2: he ; MODE 0: q
  unsigned short* outK;       // MODE 0: k
  unsigned short* outV;       // MODE 0: v^T [B,H,D,T]
};

// ---------------------------------------------------------------------------
// 128x128 tile, BK=64, 4 waves (2x2), SINGLE buffer, XOR granule swizzle.
// 32 KiB LDS -> ~5 blocks/CU; cross-block TLP hides stage drains (r8 best).
// MODE: 0=QKV scatter, 1=proj+resid, 2=fc gather+gelu, 3=pj -> pairout(f32)
// ---------------------------------------------------------------------------
template <int MODE>
__global__ __launch_bounds__(256) void gemm128b(GArgs g) {
  int e = 0, s0 = 0, Meff = g.M, row0;
  if constexpr (MODE == 2 || MODE == 3) {
    if ((int)blockIdx.y >= *g.tbl_n) return;
    e = g.tbl_e[blockIdx.y];
    row0 = g.tbl_r0[blockIdx.y];
    s0 = g.eoff[e];
    Meff = g.eoff[e + 1] - s0;
  } else {
    row0 = blockIdx.y * 128;
  }
  const int col0 = blockIdx.x * 128;

  __shared__ __align__(16) unsigned short As[128 * 64];
  __shared__ __align__(16) unsigned short Bs[128 * 64];

  const int tid = threadIdx.x;
  const int lane = tid & 63, w = tid >> 6;
  const int wr = w >> 1, wc = w & 1;
  const int fr = lane & 15, fg = lane >> 4;

  const unsigned short* Bt = g.Bt + (size_t)e * g.Bstride;
  const float* bias = g.bias + (size_t)e * g.biasStride;

  // LDS dest linear (gload_lds); GLOBAL source granule pre-swizzled (#21).
  size_t aaddr[4], baddr[4];
#pragma unroll
  for (int i = 0; i < 4; ++i) {
    int pos = i * 256 + tid;                   // 16B-granule index 0..1023
    int r = pos >> 3;                          // LDS row 0..127
    int c8 = ((pos & 7) ^ (r & 7)) * 8;        // swizzled source (elems)
    int gr = row0 + r;
    if (gr >= Meff) gr = Meff - 1;
    int srcrow;
    if constexpr (MODE == 2) srcrow = g.slot_tok[s0 + gr];
    else if constexpr (MODE == 3) srcrow = s0 + gr;
    else srcrow = gr;
    aaddr[i] = (size_t)srcrow * g.lda + c8;
    baddr[i] = (size_t)(col0 + r) * g.ldb + c8;
  }

  auto STAGE = [&](int k0) {
#pragma unroll
    for (int i = 0; i < 4; ++i) {
      GLOAD_LDS16(g.A + aaddr[i] + k0, &As[i * 2048 + w * 512]);
      GLOAD_LDS16(Bt + baddr[i] + k0, &Bs[i * 2048 + w * 512]);
    }
  };

  f32x4 acc[4][4] = {};
  const int nt = g.klen / 64;

  for (int t = 0; t < nt; ++t) {
    if (t) __syncthreads();                 // reads of prev tile complete
    STAGE(t * 64);
    __syncthreads();                        // stage-writes landed (vmcnt drain)
    b16v8 af[4][2], bf_[4][2];
#pragma unroll
    for (int mi = 0; mi < 4; ++mi) {
      const int ar = wr * 64 + mi * 16 + fr;
      af[mi][0] = *(const b16v8*)&As[swz(ar, fg)];
      af[mi][1] = *(const b16v8*)&As[swz(ar, 4 + fg)];
    }
#pragma unroll
    for (int ni = 0; ni < 4; ++ni) {
      const int br = wc * 64 + ni * 16 + fr;
      bf_[ni][0] = *(const b16v8*)&Bs[swz(br, fg)];
      bf_[ni][1] = *(const b16v8*)&Bs[swz(br, 4 + fg)];
    }
#pragma unroll
    for (int mi = 0; mi < 4; ++mi)
#pragma unroll
      for (int ni = 0; ni < 4; ++ni) {
        acc[mi][ni] = MFMA(af[mi][0], bf_[ni][0], acc[mi][ni]);
        acc[mi][ni] = MFMA(af[mi][1], bf_[ni][1], acc[mi][ni]);
      }
  }

#pragma unroll
  for (int mi = 0; mi < 4; ++mi) {
#pragma unroll
    for (int ni = 0; ni < 4; ++ni) {
#pragma unroll
      for (int rr = 0; rr < 4; ++rr) {
        int row = row0 + wr * 64 + mi * 16 + fg * 4 + rr;
        int col = col0 + wc * 64 + ni * 16 + fr;
        if (row >= Meff) continue;
        float val = acc[mi][ni][rr] + bias[col];
        if constexpr (MODE == 0) {
          int bb = row >> 11, tt = row & (Tc - 1);
          int which = col >> 10, cj = col & (Cc - 1);
          int hd = cj >> 6, d = cj & 63;
          if (which == 0)
            g.outB[(((size_t)(bb * Hc + hd)) * Tc + tt) * Dc + d] = f32_bf16(val);
          else if (which == 1)
            g.outK[(((size_t)(bb * Hc + hd)) * Tc + tt) * Dc + d] = f32_bf16(val);
          else
            g.outV[(((size_t)(bb * Hc + hd)) * Dc + d) * Tc + tt] = f32_bf16(val);
        } else if constexpr (MODE == 1) {
          size_t o = (size_t)row * g.N + col;
          g.outF[o] = val + g.resid[o];
        } else if constexpr (MODE == 2) {
          g.outB[(size_t)(s0 + row) * g.N + col] = f32_bf16(gelu_f(val));
        } else {
          g.outF[(size_t)(s0 + row) * g.N + col] = val;
        }
      }
    }
  }
}

// ---------------------------------------------------------------------------
// Flash-style causal attention. 8 waves, 128 q-rows, KV tile 64.
// Heavy-first dispatch (qt reversed). T14 reg-prefetch of next K/V tile.
// ---------------------------------------------------------------------------
__global__ __launch_bounds__(512) void attn_kernel(
    const unsigned short* __restrict__ q, const unsigned short* __restrict__ k,
    const unsigned short* __restrict__ v, unsigned short* __restrict__ y) {
  const int qt = gridDim.x - 1 - blockIdx.x;   // heavy-first
  const int bh = blockIdx.y;
  const int qbase = qt * 128;
  __shared__ __align__(16) unsigned short ldsK[64][72];
  __shared__ __align__(16) unsigned short ldsVT[64][72];     // [d][kv]
  __shared__ __align__(16) unsigned short ldsP[8][16][72];
  const int tid = threadIdx.x, lane = tid & 63, w = tid >> 6;
  const int fr = lane & 15, fg = lane >> 4;
  const size_t base = (size_t)bh * Tc * Dc;
  const int qrow = qbase + w * 16 + fr;
  b16v8 qa0 = *(const b16v8*)(q + base + (size_t)qrow * Dc + fg * 8);
  b16v8 qa1 = *(const b16v8*)(q + base + (size_t)qrow * Dc + 32 + fg * 8);
  float m[4], lsum[4] = {0.f, 0.f, 0.f, 0.f};
#pragma unroll
  for (int r = 0; r < 4; ++r) m[r] = -3.0e38f;
  f32x4 oacc[4] = {};
  constexpr float SC = 0.125f * LOG2E;

  const int sr = tid >> 3, scb = (tid & 7) * 8;
  const int ntile = (qbase + 128) / 64;

  *(uint4*)&ldsK[sr][scb]  = *(const uint4*)(k + base + (size_t)sr * Dc + scb);
  *(uint4*)&ldsVT[sr][scb] = *(const uint4*)(v + base + (size_t)sr * Tc + scb);
  __syncthreads();

  for (int ti = 0; ti < ntile; ++ti) {
    const int kb = ti * 64;
    uint4 kreg, vreg;
    const bool more = (ti + 1 < ntile);
    if (more) {
      const int kn = kb + 64;
      kreg = *(const uint4*)(k + base + (size_t)(kn + sr) * Dc + scb);
      vreg = *(const uint4*)(v + base + (size_t)sr * Tc + kn + scb);
    }

    f32x4 s[4];
#pragma unroll
    for (int ni = 0; ni < 4; ++ni) {
      b16v8 kb0 = *(const b16v8*)&ldsK[ni * 16 + fr][fg * 8];
      b16v8 kb1 = *(const b16v8*)&ldsK[ni * 16 + fr][32 + fg * 8];
      f32x4 z = {};
      z = MFMA(qa0, kb0, z);
      z = MFMA(qa1, kb1, z);
      s[ni] = z;
    }
    const bool diag = (kb + 64 > qbase + w * 16);
#pragma unroll
    for (int ni = 0; ni < 4; ++ni) {
#pragma unroll
      for (int r = 0; r < 4; ++r) {
        float sv = s[ni][r] * SC;
        if (diag) {
          int gq = qbase + w * 16 + fg * 4 + r;
          int kv = kb + ni * 16 + fr;
          if (kv > gq) sv = -3.0e38f;
        }
        s[ni][r] = sv;
      }
    }
#pragma unroll
    for (int r = 0; r < 4; ++r) {
      float mx = fmaxf(fmaxf(s[0][r], s[1][r]), fmaxf(s[2][r], s[3][r]));
#pragma unroll
      for (int msk = 1; msk <= 8; msk <<= 1) mx = fmaxf(mx, __shfl_xor(mx, msk));
      float mnew = fmaxf(m[r], mx);
      float alpha = __builtin_amdgcn_exp2f(m[r] - mnew);
      float psum = 0.f;
#pragma unroll
      for (int ni = 0; ni < 4; ++ni) {
        float pp = __builtin_amdgcn_exp2f(s[ni][r] - mnew);
        s[ni][r] = pp;
        psum += pp;
      }
#pragma unroll
      for (int msk = 1; msk <= 8; msk <<= 1) psum += __shfl_xor(psum, msk);
      lsum[r] = lsum[r] * alpha + psum;
      m[r] = mnew;
#pragma unroll
      for (int ni = 0; ni < 4; ++ni) {
        oacc[ni][r] = oacc[ni][r] * alpha;
        ldsP[w][fg * 4 + r][ni * 16 + fr] = f32_bf16(s[ni][r]);
      }
    }
    asm volatile("s_waitcnt lgkmcnt(0)" ::: "memory");
    __builtin_amdgcn_sched_barrier(0);
    b16v8 pa0 = *(const b16v8*)&ldsP[w][fr][fg * 8];
    b16v8 pa1 = *(const b16v8*)&ldsP[w][fr][32 + fg * 8];
#pragma unroll
    for (int ni = 0; ni < 4; ++ni) {
      b16v8 vb0 = *(const b16v8*)&ldsVT[ni * 16 + fr][fg * 8];
      b16v8 vb1 = *(const b16v8*)&ldsVT[ni * 16 + fr][32 + fg * 8];
      oacc[ni] = MFMA(pa0, vb0, oacc[ni]);
      oacc[ni] = MFMA(pa1, vb1, oacc[ni]);
    }

    if (more) {
      __syncthreads();
      *(uint4*)&ldsK[sr][scb]  = kreg;
      *(uint4*)&ldsVT[sr][scb] = vreg;
      __syncthreads();
    }
  }

  const int bb = bh >> 4, hh = bh & 15;
#pragma unroll
  for (int r = 0; r < 4; ++r) {
    float rl = __builtin_amdgcn_rcpf(lsum[r]);
#pragma unroll
    for (int ni = 0; ni < 4; ++ni) {
      int t = qbase + w * 16 + fg * 4 + r;
      int d = ni * 16 + fr;
      y[((size_t)(bb * Tc + t)) * Cc + hh * Dc + d] = f32_bf16(oacc[ni][r] * rl);
    }
  }
}

// ---------------------------------------------------------------------------
// Deterministic combine: out[n] += p0*pair[s0] + p1*pair[s1]
// ---------------------------------------------------------------------------
__global__ __launch_bounds__(256) void combine_kernel(
    const float* __restrict__ pair, const float* __restrict__ tkp,
    const int* __restrict__ tok2slot, float* __restrict__ out) {
  const int n = blockIdx.x;
  const int c4 = threadIdx.x * 4;
  const int s0 = tok2slot[n * 2], s1 = tok2slot[n * 2 + 1];
  const float p0 = tkp[n * 2], p1 = tkp[n * 2 + 1];
  float4 a = *(const float4*)&pair[(size_t)s0 * Cc + c4];
  float4 b = *(const float4*)&pair[(size_t)s1 * Cc + c4];
  float4 o = *(float4*)&out[(size_t)n * Cc + c4];
  o.x += p0 * a.x + p1 * b.x;
  o.y += p0 * a.y + p1 * b.y;
  o.z += p0 * a.z + p1 * b.z;
  o.w += p0 * a.w + p1 * b.w;
  *(float4*)&out[(size_t)n * Cc + c4] = o;
}

// ---------------------------------------------------------------------------
extern "C" void kernel_launch(void* const* d_in, const int* in_sizes, int n_in,
                              void* d_out, int out_size, void* d_ws, size_t ws_size,
                              hipStream_t stream) {
  const float* x        = (const float*)d_in[0];
  const float* ln1_g    = (const float*)d_in[1];
  const float* ln1_b    = (const float*)d_in[2];
  const float* ln2_g    = (const float*)d_in[3];
  const float* ln2_b    = (const float*)d_in[4];
  const float* attn_w   = (const float*)d_in[5];
  const float* attn_b   = (const float*)d_in[6];
  const float* proj_w   = (const float*)d_in[7];
  const float* proj_b   = (const float*)d_in[8];
  const float* router_w = (const float*)d_in[9];
  const float* fc_w     = (const float*)d_in[10];
  const float* fc_b     = (const float*)d_in[11];
  const float* pj_w     = (const float*)d_in[12];
  const float* pj_b     = (const float*)d_in[13];
  float* out = (float*)d_out;

  char* ws = (char*)d_ws;
  size_t off = 0;
  auto alloc = [&](size_t bytes) -> void* {
    void* p = ws + off;
    off = (off + bytes + 255) & ~(size_t)255;
    return p;
  };
  unsigned short* attn_wT = (unsigned short*)alloc((size_t)3 * Cc * Cc * 2);
  unsigned short* proj_wT = (unsigned short*)alloc((size_t)Cc * Cc * 2);
  unsigned short* fc_wT   = (unsigned short*)alloc((size_t)Ec * HIDc * Cc * 2);
  unsigned short* pj_wT   = (unsigned short*)alloc((size_t)Ec * Cc * HIDc * 2);
  unsigned short* h    = (unsigned short*)alloc((size_t)Nc * Cc * 2);
  unsigned short* qb   = (unsigned short*)alloc((size_t)Nc * Cc * 2);   // [B,H,T,D]
  unsigned short* kbuf = (unsigned short*)alloc((size_t)Nc * Cc * 2);   // [B,H,T,D]
  unsigned short* vbuf = (unsigned short*)alloc((size_t)Nc * Cc * 2);   // [B,H,D,T]
  unsigned short* ybuf = (unsigned short*)alloc((size_t)Nc * Cc * 2);   // [N,C]
  unsigned short* he   = (unsigned short*)alloc((size_t)NPAIR * HIDc * 2);
  float* pairout = (float*)alloc((size_t)NPAIR * Cc * 4);
  int*   tki     = (int*)alloc((size_t)Nc * 2 * 4);
  float* tkp     = (float*)alloc((size_t)Nc * 2 * 4);
  int*   counts  = (int*)alloc(Ec * 4);
  int*   eoff    = (int*)alloc((Ec + 1) * 4);
  int*   cursor  = (int*)alloc(Ec * 4);
  int*   slot_tok= (int*)alloc((size_t)NPAIR * 4);
  int*   tok2slot= (int*)alloc((size_t)Nc * 2 * 4);
  int*   tbl_e   = (int*)alloc(NRBMAX * 4);
  int*   tbl_r0  = (int*)alloc(NRBMAX * 4);
  int*   tbl_n   = (int*)alloc(4);
  (void)ws_size; (void)in_sizes; (void)n_in; (void)out_size;

  // 0) weight pre-transpose/convert (64x64 tiles)
  convT_kernel<<<dim3(3 * Cc / 64, Cc / 64, 1), 256, 0, stream>>>(attn_w, attn_wT, Cc, 3 * Cc);
  convT_kernel<<<dim3(Cc / 64, Cc / 64, 1), 256, 0, stream>>>(proj_w, proj_wT, Cc, Cc);
  convT_kernel<<<dim3(HIDc / 64, Cc / 64, Ec), 256, 0, stream>>>(fc_w, fc_wT, Cc, HIDc);
  convT_kernel<<<dim3(Cc / 64, HIDc / 64, Ec), 256, 0, stream>>>(pj_w, pj_wT, HIDc, Cc);

  // 1) LN1
  ln1_kernel<<<Nc, 256, 0, stream>>>(x, ln1_g, ln1_b, h);

  // 2) QKV GEMM -> q/k [B,H,T,D], v^T [B,H,D,T]
  {
    GArgs a = {};
    a.A = h; a.Bt = attn_wT; a.bias = attn_b;
    a.M = Nc; a.N = 3 * Cc; a.K = Cc; a.lda = Cc; a.ldb = Cc; a.klen = Cc;
    a.outB = qb; a.outK = kbuf; a.outV = vbuf;
    gemm128b<0><<<dim3(3 * Cc / 128, Nc / 128, 1), 256, 0, stream>>>(a);
  }

  // 3) causal attention -> y [N,C] bf16 (heavy-first)
  attn_kernel<<<dim3(Tc / 128, Bc * Hc), 512, 0, stream>>>(qb, kbuf, vbuf, ybuf);

  // 4) proj + residual -> d_out (f32)
  {
    GArgs p = {};
    p.A = ybuf; p.Bt = proj_wT; p.bias = proj_b;
    p.M = Nc; p.N = Cc; p.K = Cc; p.lda = Cc; p.ldb = Cc; p.klen = Cc;
    p.outF = out; p.resid = x;
    gemm128b<1><<<dim3(Cc / 128, Nc / 128, 1), 256, 0, stream>>>(p);
  }

  // 5) LN2 + router -> h (bf16), top-2
  ln2_router_kernel<<<Nc, 256, 0, stream>>>(out, ln2_g, ln2_b, router_w, h, tki, tkp);

  // 6) routing lists (slot-compacted pairs) + rowblock table
  hipMemsetAsync(counts, 0, Ec * sizeof(int), stream);
  count_kernel<<<(Nc + 255) / 256, 256, 0, stream>>>(tki, counts);
  scan_kernel<<<1, 64, 0, stream>>>(counts, eoff, cursor, tbl_e, tbl_r0, tbl_n);
  assign_kernel<<<(Nc + 255) / 256, 256, 0, stream>>>(tki, cursor, slot_tok, tok2slot);

  // 7) fc -> he [NPAIR][HID] bf16 w/ GELU (exact rowblock grid)
  {
    GArgs f = {};
    f.A = h; f.Bt = fc_wT; f.bias = fc_b;
    f.M = Nc; f.N = HIDc; f.K = Cc; f.lda = Cc; f.ldb = Cc; f.klen = Cc;
    f.Bstride = (size_t)HIDc * Cc; f.biasStride = HIDc;
    f.eoff = eoff; f.slot_tok = slot_tok;
    f.tbl_e = tbl_e; f.tbl_r0 = tbl_r0; f.tbl_n = tbl_n;
    f.outB = he;
    gemm128b<2><<<dim3(HIDc / 128, NRBMAX, 1), 256, 0, stream>>>(f);
  }

  // 8) pj (single K pass) -> pairout [NPAIR][C] f32 (bias incl.)
  {
    GArgs pj = {};
    pj.A = he; pj.Bt = pj_wT; pj.bias = pj_b;
    pj.M = Nc; pj.N = Cc; pj.K = HIDc; pj.lda = HIDc; pj.ldb = HIDc; pj.klen = HIDc;
    pj.Bstride = (size_t)Cc * HIDc; pj.biasStride = Cc;
    pj.eoff = eoff; pj.slot_tok = slot_tok;
    pj.tbl_e = tbl_e; pj.tbl_r0 = tbl_r0; pj.tbl_n = tbl_n;
    pj.outF = pairout;
    gemm128b<3><<<dim3(Cc / 128, NRBMAX, 1), 256, 0, stream>>>(pj);
  }

  // 9) deterministic combine into d_out
  combine_kernel<<<Nc, 256, 0, stream>>>(pairout, tkp, tok2slot, out);
}